// Round 16
// baseline (675.245 us; speedup 1.0000x reference)
//
#include <hip/hip_runtime.h>
#include <hip/hip_bf16.h>

#define DEV static __device__ __forceinline__

typedef __attribute__((ext_vector_type(8))) short short8;
typedef __attribute__((ext_vector_type(4))) short short4s;
typedef __attribute__((ext_vector_type(8))) __bf16 bf16x8;
typedef __attribute__((ext_vector_type(4))) float floatx4;

DEV short f2bf(float f) {
  unsigned u = __builtin_bit_cast(unsigned, f);
  unsigned r = (u + 0x7fffu + ((u >> 16) & 1u)) >> 16;
  return (short)(unsigned short)r;
}
DEV float bf2f(short s) {
  unsigned u = ((unsigned)(unsigned short)s) << 16;
  return __builtin_bit_cast(float, u);
}
DEV floatx4 mfma16(short8 a, short8 b, floatx4 c) {
  return __builtin_amdgcn_mfma_f32_16x16x32_bf16(
      __builtin_bit_cast(bf16x8, a), __builtin_bit_cast(bf16x8, b), c, 0, 0, 0);
}

#define VMCNT(n) asm volatile("s_waitcnt vmcnt(" #n ")" ::: "memory")
#define SBAR() __builtin_amdgcn_s_barrier()

// ---------------- GEMM staging: [rows][32] bf16 tiles, pre-swizzled source ----------
DEV int sw2(int r) { return (r ^ (r >> 2)) & 3; }

DEV const short* sbase(const short* src, int ld, int row0, int id) {
  int r = id >> 2, cc = id & 3;
  return src + (long)(row0 + r) * ld + ((cc ^ sw2(r)) << 3);
}
DEV void sissue(short* ldsbuf, const short* base, int k0, int tid, int slotbase) {
  int wave = tid >> 6;
  __builtin_amdgcn_global_load_lds(
      (const __attribute__((address_space(1))) void*)(base + k0),
      (__attribute__((address_space(3))) void*)(ldsbuf + (slotbase + wave * 64) * 8),
      16, 0, 0);
}
DEV short8 rdfrag(const short* lds, int row, int l4) {
  return *(const short8*)(lds + row * 32 + ((l4 ^ sw2(row)) << 3));
}

// ---------------- BK=64 staging: [rows][64] bf16 tiles, chunk swizzle c^(r&7) -------
DEV const short* sb64(const short* src, int ld, int row0, int id) {
  int r = id >> 3, c = id & 7;
  return src + (long)(row0 + r) * ld + ((c ^ (r & 7)) << 3);
}
DEV const short* sb64g(const short* src, int ld, const int* rows, int p0, int plim,
                       int id) {
  int r = id >> 3, c = id & 7;
  int pi = p0 + r;
  if (pi > plim) pi = plim;
  return src + (long)rows[pi] * ld + ((c ^ (r & 7)) << 3);
}
DEV short8 rd64(const short* lds, int row, int ch) {
  return *(const short8*)(lds + row * 64 + ((ch ^ (row & 7)) << 3));
}

// ---------------- transpose helpers -------------------------------------------------
DEV void trans_load(const float* src, int N, int n0, int k0, float (*t)[65], int tid) {
  int r = tid >> 2, cq = tid & 3;
  const float* s = src + (long)(k0 + r) * N + n0 + cq * 16;
#pragma unroll
  for (int i = 0; i < 4; ++i) {
    float4 v = *(const float4*)(s + i * 4);
    t[r][cq * 16 + i * 4 + 0] = v.x;
    t[r][cq * 16 + i * 4 + 1] = v.y;
    t[r][cq * 16 + i * 4 + 2] = v.z;
    t[r][cq * 16 + i * 4 + 3] = v.w;
  }
}

DEV void trans_tile1(const float* src, short* dst, int N, int K, int n0, int k0,
                     float (*t)[65]) {
  int tid = threadIdx.x;
  trans_load(src, N, n0, k0, t, tid);
  __syncthreads();
  int n = tid >> 2, kc = tid & 3;
#pragma unroll
  for (int ii = 0; ii < 2; ++ii) {
    short8 o;
#pragma unroll
    for (int j = 0; j < 8; ++j) o[j] = f2bf(t[kc * 16 + ii * 8 + j][n]);
    *(short8*)(dst + (long)(n0 + n) * K + k0 + kc * 16 + ii * 8) = o;
  }
}

DEV void trans_tile2(const float* src, short* dh, short* dl, int N, int K, int n0,
                     int k0, float (*t)[65]) {
  int tid = threadIdx.x;
  trans_load(src, N, n0, k0, t, tid);
  __syncthreads();
  int n = tid >> 2, kc = tid & 3;
#pragma unroll
  for (int ii = 0; ii < 2; ++ii) {
    short8 ohv, olv;
#pragma unroll
    for (int j = 0; j < 8; ++j) {
      float v = t[kc * 16 + ii * 8 + j][n];
      short hi = f2bf(v);
      ohv[j] = hi;
      olv[j] = f2bf(v - bf2f(hi));
    }
    *(short8*)(dh + (long)(n0 + n) * K + k0 + kc * 16 + ii * 8) = ohv;
    *(short8*)(dl + (long)(n0 + n) * K + k0 + kc * 16 + ii * 8) = olv;
  }
}

// ---------------- upfront: qkv weight transpose + rmsnorm1 --------------------------
__global__ __launch_bounds__(256) void k_trans_pre(
    const float* wq, const float* wk, const float* wv,
    short* qkvTh, short* qkvTl,
    const float* x, const float* ln1, short* hbh, short* hbl) {
  __shared__ float t[64][65];
  __shared__ float red[4];
  int bid = blockIdx.x;
  if (bid < 1536) {
    int xx = bid % 48, kt = bid / 48;
    const float* src; short* dh; short* dl; int N, n0;
    if (xx < 32)      { src = wq; dh = qkvTh; dl = qkvTl; N = 2048; n0 = xx * 64; }
    else if (xx < 40) { src = wk; dh = qkvTh + 2048L * 2048; dl = qkvTl + 2048L * 2048;
                        N = 512; n0 = (xx - 32) * 64; }
    else              { src = wv; dh = qkvTh + 2560L * 2048; dl = qkvTl + 2560L * 2048;
                        N = 512; n0 = (xx - 40) * 64; }
    trans_tile2(src, dh, dl, N, 2048, n0, kt * 64, t);
  } else {
    int row = bid - 1536, tid = threadIdx.x;
    const float* xr = x + (long)row * 2048;
    float4 a = *(const float4*)(xr + tid * 8);
    float4 c = *(const float4*)(xr + tid * 8 + 4);
    float ss = a.x * a.x + a.y * a.y + a.z * a.z + a.w * a.w +
               c.x * c.x + c.y * c.y + c.z * c.z + c.w * c.w;
    ss += __shfl_xor(ss, 1);  ss += __shfl_xor(ss, 2);  ss += __shfl_xor(ss, 4);
    ss += __shfl_xor(ss, 8);  ss += __shfl_xor(ss, 16); ss += __shfl_xor(ss, 32);
    int wave = tid >> 6;
    if ((tid & 63) == 0) red[wave] = ss;
    __syncthreads();
    float tot = red[0] + red[1] + red[2] + red[3];
    float inv = 1.f / sqrtf(tot * (1.f / 2048.f) + 1e-6f);
    float4 w0 = *(const float4*)(ln1 + tid * 8);
    float4 w1v = *(const float4*)(ln1 + tid * 8 + 4);
    float xv[8] = {a.x * w0.x, a.y * w0.y, a.z * w0.z, a.w * w0.w,
                   c.x * w1v.x, c.y * w1v.y, c.z * w1v.z, c.w * w1v.w};
    short8 ohv, olv;
#pragma unroll
    for (int j = 0; j < 8; ++j) {
      float v = xv[j] * inv;
      short hi = f2bf(v);
      ohv[j] = hi;
      olv[j] = f2bf(v - bf2f(hi));
    }
    *(short8*)(hbh + (long)row * 2048 + tid * 8) = ohv;
    *(short8*)(hbl + (long)row * 2048 + tid * 8) = olv;
  }
}

// ---------------- QKV GEMM (768) interleaved with ALL remaining transposes ----------
// 14080 blocks: groups of 18 = 1 qkv + 17 trans tiles; 256 tail trans tiles.
// trans tiles: ti 0..1023 = wo; 1024..9215 = w1/w3; 9216..13311 = w2.
__global__ __launch_bounds__(256) void k_qkv_plus(
    const short* Ah, const short* Al, const short* Bh, const short* Bl,
    short* qbh, short* qbl, short* kbh, short* kbl, short* vth, short* vtl,
    const float* cs, const float* sn,
    const float* wo, short* woTh, short* woTl,
    const float* w1, const float* w3, const float* w2,
    short* w1T, short* w3T, short* w2T) {
  __shared__ __align__(16) char smem[49152];
  int bid = blockIdx.x;
  int qi = -1, ti = -1;
  if (bid < 13824) {
    int grp = bid / 18, rem = bid % 18;
    if (rem == 0) qi = grp;
    else ti = grp * 17 + (rem - 1);
  } else {
    ti = 13056 + (bid - 13824);
  }
  if (ti >= 0) {
    float (*t)[65] = (float(*)[65])smem;
    if (ti < 1024) {
      int xx = ti & 31, kt = ti >> 5;
      trans_tile2(wo, woTh, woTl, 2048, 2048, xx * 64, kt * 64, t);
    } else if (ti < 9216) {
      int mi2 = ti - 1024;
      int xx = mi2 % 256, kt = mi2 / 256;
      const float* src; short* dst; int n0;
      if (xx < 128) { int e = xx >> 4; src = w1 + (long)e * 2048 * 1024;
                      dst = w1T + (long)e * 1024 * 2048; n0 = (xx & 15) * 64; }
      else          { int x2 = xx - 128, e = x2 >> 4; src = w3 + (long)e * 2048 * 1024;
                      dst = w3T + (long)e * 1024 * 2048; n0 = (x2 & 15) * 64; }
      trans_tile1(src, dst, 1024, 2048, n0, kt * 64, t);
    } else {
      int i = ti - 9216;
      int xx = i % 256, kt = i / 256;
      int e = xx >> 5, ntb = xx & 31;
      trans_tile1(w2 + (long)e * 1024 * 2048, w2T + (long)e * 2048 * 1024,
                  2048, 1024, ntb * 64, kt * 64, t);
    }
    return;
  }
  const int K = 2048;
  short* AsH = (short*)smem;      // [2][2048]
  short* AsL = AsH + 4096;
  short* BsH = AsL + 4096;        // [2][4096]
  short* BsL = BsH + 8192;
  int tid = threadIdx.x, lane = tid & 63, wave = tid >> 6;
  int l15 = lane & 15, l4 = lane >> 4;
  int wm = wave >> 1, wn = wave & 1;
  int swz = (qi & 7) * 96 + (qi >> 3);
  int bx = swz % 24, by = swz / 24;
  int m0 = by * 64, n0 = bx * 128;

  const short* bA_H = sbase(Ah, K, m0, tid);
  const short* bA_L = sbase(Al, K, m0, tid);
  const short* bBH0 = sbase(Bh, K, n0, tid);
  const short* bBH1 = sbase(Bh, K, n0, tid + 256);
  const short* bBL0 = sbase(Bl, K, n0, tid);
  const short* bBL1 = sbase(Bl, K, n0, tid + 256);

  auto STAGE = [&](int buf, int k0) {
    sissue(AsH + buf * 2048, bA_H, k0, tid, 0);
    sissue(AsL + buf * 2048, bA_L, k0, tid, 0);
    sissue(BsH + buf * 4096, bBH0, k0, tid, 0);
    sissue(BsH + buf * 4096, bBH1, k0, tid, 256);
    sissue(BsL + buf * 4096, bBL0, k0, tid, 0);
    sissue(BsL + buf * 4096, bBL1, k0, tid, 256);
  };

  floatx4 zero4 = {0.f, 0.f, 0.f, 0.f};
  floatx4 acc[2][4];
#pragma unroll
  for (int i = 0; i < 2; ++i)
#pragma unroll
    for (int j = 0; j < 4; ++j) acc[i][j] = zero4;

  STAGE(0, 0);
  STAGE(1, 32);
  int cur = 0;
  for (int k0 = 0; k0 < K; k0 += 32) {
    if (k0 + 64 < K) VMCNT(6); else VMCNT(0);
    SBAR();
    short8 ah[2], al[2], bh2[4], bl2[4];
#pragma unroll
    for (int mi = 0; mi < 2; ++mi) {
      ah[mi] = rdfrag(AsH + cur * 2048, wm * 32 + mi * 16 + l15, l4);
      al[mi] = rdfrag(AsL + cur * 2048, wm * 32 + mi * 16 + l15, l4);
    }
#pragma unroll
    for (int nt = 0; nt < 4; ++nt) {
      bh2[nt] = rdfrag(BsH + cur * 4096, wn * 64 + nt * 16 + l15, l4);
      bl2[nt] = rdfrag(BsL + cur * 4096, wn * 64 + nt * 16 + l15, l4);
    }
#pragma unroll
    for (int mi = 0; mi < 2; ++mi)
#pragma unroll
      for (int nt = 0; nt < 4; ++nt) {
        acc[mi][nt] = mfma16(al[mi], bh2[nt], acc[mi][nt]);
        acc[mi][nt] = mfma16(ah[mi], bl2[nt], acc[mi][nt]);
        acc[mi][nt] = mfma16(ah[mi], bh2[nt], acc[mi][nt]);
      }
    SBAR();
    if (k0 + 64 < K) STAGE(cur, k0 + 64);
    cur ^= 1;
  }

  int p = (n0 >> 6) + wn;  // 64-col panel = one head
  bool isq = p < 32, isk = (!isq) && p < 40;
  if (isq || isk) {
#pragma unroll
    for (int mi = 0; mi < 2; ++mi)
#pragma unroll
      for (int ntp = 0; ntp < 2; ++ntp)
#pragma unroll
        for (int j = 0; j < 4; ++j) {
          int row = m0 + wm * 32 + mi * 16 + l4 * 4 + j;
          int d = ntp * 16 + l15;
          float x0 = acc[mi][ntp][j], x1 = acc[mi][ntp + 2][j];
          float c0 = cs[row * 64 + d], c1 = cs[row * 64 + d + 32];
          float s0 = sn[row * 64 + d], s1 = sn[row * 64 + d + 32];
          float y0 = x0 * c0 - x1 * s0;
          float y1 = x1 * c1 + x0 * s1;
          if (isq) { y0 *= 0.125f; y1 *= 0.125f; }
          acc[mi][ntp][j] = y0;
          acc[mi][ntp + 2][j] = y1;
        }
    short* Ch; short* Cl; int ldc, coff;
    if (isq) { Ch = qbh; Cl = qbl; ldc = 2048; coff = p * 64; }
    else     { Ch = kbh; Cl = kbl; ldc = 512;  coff = (p - 32) * 64; }
#pragma unroll
    for (int mi = 0; mi < 2; ++mi)
#pragma unroll
      for (int nt = 0; nt < 4; ++nt) {
        int row = m0 + wm * 32 + mi * 16 + l4 * 4;
        int col = coff + nt * 16 + l15;
#pragma unroll
        for (int j = 0; j < 4; ++j) {
          float v = acc[mi][nt][j];
          long ix = (long)(row + j) * ldc + col;
          short hi = f2bf(v);
          Ch[ix] = hi;
          Cl[ix] = f2bf(v - bf2f(hi));
        }
      }
  } else {
    int kvh = p - 40;
#pragma unroll
    for (int mi = 0; mi < 2; ++mi)
#pragma unroll
      for (int nt = 0; nt < 4; ++nt) {
        int row0 = m0 + wm * 32 + mi * 16 + l4 * 4;
        int d = nt * 16 + l15;
        int bb = row0 >> 10, tt = row0 & 1023;
        long base = ((long)(bb * 8 + kvh)) * 65536 + (long)d * 1024 + tt;
        short4s hv, lv;
#pragma unroll
        for (int j = 0; j < 4; ++j) {
          float v = acc[mi][nt][j];
          short hi = f2bf(v);
          hv[j] = hi;
          lv[j] = f2bf(v - bf2f(hi));
        }
        *(short4s*)(vth + base) = hv;
        *(short4s*)(vtl + base) = lv;
      }
  }
}

// ---------------- WO split GEMM + residual: BM=128, BN=64, counted-vmcnt, XCD swz ---
__global__ __launch_bounds__(256) void k_gemm_wo(const short* Ah, const short* Al,
                                                 const short* Bh, const short* Bl,
                                                 const float* resid, float* out) {
  const int K = 2048;
  __shared__ __align__(16) short AsH[2][4096], AsL[2][4096], BsH[2][2048], BsL[2][2048];
  int tid = threadIdx.x, lane = tid & 63, wave = tid >> 6;
  int l15 = lane & 15, l4 = lane >> 4;
  int bid = blockIdx.y * 32 + blockIdx.x;
  int swz = (bid & 7) * 64 + (bid >> 3);
  int bx = swz % 32, by = swz / 32;
  int m0 = by * 128, n0 = bx * 64;

  const short* bAH0 = sbase(Ah, K, m0, tid);
  const short* bAH1 = sbase(Ah, K, m0, tid + 256);
  const short* bAL0 = sbase(Al, K, m0, tid);
  const short* bAL1 = sbase(Al, K, m0, tid + 256);
  const short* bBH0 = sbase(Bh, K, n0, tid);
  const short* bBL0 = sbase(Bl, K, n0, tid);

  auto STAGE = [&](int buf, int k0) {
    sissue(AsH[buf], bAH0, k0, tid, 0);
    sissue(AsH[buf], bAH1, k0, tid, 256);
    sissue(AsL[buf], bAL0, k0, tid, 0);
    sissue(AsL[buf], bAL1, k0, tid, 256);
    sissue(BsH[buf], bBH0, k0, tid, 0);
    sissue(BsL[buf], bBL0, k0, tid, 0);
  };

  floatx4 zero4 = {0.f, 0.f, 0.f, 0.f};
  floatx4 acc[2][4];
#pragma unroll
  for (int i = 0; i < 2; ++i)
#pragma unroll
    for (int j = 0; j < 4; ++j) acc[i][j] = zero4;

  STAGE(0, 0);
  STAGE(1, 32);
  int cur = 0;
  for (int k0 = 0; k0 < K; k0 += 32) {
    if (k0 + 64 < K) VMCNT(6); else VMCNT(0);
    SBAR();
    short8 ah[2], al[2], bh2[4], bl2[4];
#pragma unroll
    for (int mi = 0; mi < 2; ++mi) {
      ah[mi] = rdfrag(AsH[cur], wave * 32 + mi * 16 + l15, l4);
      al[mi] = rdfrag(AsL[cur], wave * 32 + mi * 16 + l15, l4);
    }
#pragma unroll
    for (int nt = 0; nt < 4; ++nt) {
      bh2[nt] = rdfrag(BsH[cur], nt * 16 + l15, l4);
      bl2[nt] = rdfrag(BsL[cur], nt * 16 + l15, l4);
    }
#pragma unroll
    for (int mi = 0; mi < 2; ++mi)
#pragma unroll
      for (int nt = 0; nt < 4; ++nt) {
        acc[mi][nt] = mfma16(al[mi], bh2[nt], acc[mi][nt]);
        acc[mi][nt] = mfma16(ah[mi], bl2[nt], acc[mi][nt]);
        acc[mi][nt] = mfma16(ah[mi], bh2[nt], acc[mi][nt]);
      }
    SBAR();
    if (k0 + 64 < K) STAGE(cur, k0 + 64);
    cur ^= 1;
  }
#pragma unroll
  for (int mi = 0; mi < 2; ++mi)
#pragma unroll
    for (int nt = 0; nt < 4; ++nt) {
      int row = m0 + wave * 32 + mi * 16 + l4 * 4;
      int col = n0 + nt * 16 + l15;
#pragma unroll
      for (int j = 0; j < 4; ++j) {
        long ix = (long)(row + j) * 2048 + col;
        out[ix] = resid[ix] + acc[mi][nt][j];
      }
    }
}

// ---------------- MoE grouped GEMM A: BM=128, BN=64, BK=64, counted-vmcnt -----------
__global__ __launch_bounds__(256) void k_moe_a(const short* X, const short* W1T,
                                               const short* W3T, const int* rows,
                                               const int* cnt, const int* eoff,
                                               short* hh) {
  int e = blockIdx.z;
  int c = cnt[e];
  int mtile = blockIdx.y;
  if (mtile * 128 >= c) return;
  int p0 = eoff[e] + mtile * 128;
  int plim = eoff[e] + c - 1;
  const short* B1 = W1T + (long)e * 1024 * 2048;
  const short* B3 = W3T + (long)e * 1024 * 2048;
  int n0 = blockIdx.x * 64;
  __shared__ __align__(16) short As_[2][8192], B1s[2][4096], B3s[2][4096];
  int tid = threadIdx.x, lane = tid & 63, wave = tid >> 6;
  int l15 = lane & 15, l4 = lane >> 4;
  int wm = wave >> 1, wn = wave & 1;

  const short* bA0 = sb64g(X, 2048, rows, p0, plim, tid);
  const short* bA1 = sb64g(X, 2048, rows, p0, plim, tid + 256);
  const short* bA2 = sb64g(X, 2048, rows, p0, plim, tid + 512);
  const short* bA3 = sb64g(X, 2048, rows, p0, plim, tid + 768);
  const short* bB1_0 = sb64(B1, 2048, n0, tid);
  const short* bB1_1 = sb64(B1, 2048, n0, tid + 256);
  const short* bB3_0 = sb64(B3, 2048, n0, tid);
  const short* bB3_1 = sb64(B3, 2048, n0, tid + 256);

  auto STAGE = [&](int buf, int k0) {
    sissue(As_[buf], bA0, k0, tid, 0);
    sissue(As_[buf], bA1, k0, tid, 256);
    sissue(As_[buf], bA2, k0, tid, 512);
    sissue(As_[buf], bA3, k0, tid, 768);
    sissue(B1s[buf], bB1_0, k0, tid, 0);
    sissue(B1s[buf], bB1_1, k0, tid, 256);
    sissue(B3s[buf], bB3_0, k0, tid, 0);
    sissue(B3s[buf], bB3_1, k0, tid, 256);
  };

  floatx4 zero4 = {0.f, 0.f, 0.f, 0.f};
  floatx4 acc1[4][2], acc3[4][2];
#pragma unroll
  for (int i = 0; i < 4; ++i)
#pragma unroll
    for (int j = 0; j < 2; ++j) { acc1[i][j] = zero4; acc3[i][j] = zero4; }

  STAGE(0, 0);
  STAGE(1, 64);
  int cur = 0;
  for (int k0 = 0; k0 < 2048; k0 += 64) {
    if (k0 + 128 < 2048) VMCNT(8); else VMCNT(0);
    SBAR();
#pragma unroll
    for (int kh = 0; kh < 2; ++kh) {
      int ch = kh * 4 + l4;
      short8 af[4], b1f[2], b3f[2];
#pragma unroll
      for (int mi = 0; mi < 4; ++mi)
        af[mi] = rd64(As_[cur], wm * 64 + mi * 16 + l15, ch);
#pragma unroll
      for (int nt = 0; nt < 2; ++nt) {
        b1f[nt] = rd64(B1s[cur], wn * 32 + nt * 16 + l15, ch);
        b3f[nt] = rd64(B3s[cur], wn * 32 + nt * 16 + l15, ch);
      }
#pragma unroll
      for (int mi = 0; mi < 4; ++mi)
#pragma unroll
        for (int nt = 0; nt < 2; ++nt) {
          acc1[mi][nt] = mfma16(af[mi], b1f[nt], acc1[mi][nt]);
          acc3[mi][nt] = mfma16(af[mi], b3f[nt], acc3[mi][nt]);
        }
    }
    SBAR();
    if (k0 + 128 < 2048) STAGE(cur, k0 + 128);
    cur ^= 1;
  }
#pragma unroll
  for (int mi = 0; mi < 4; ++mi)
#pragma unroll
    for (int nt = 0; nt < 2; ++nt) {
      int col = n0 + wn * 32 + nt * 16 + l15;
#pragma unroll
      for (int j = 0; j < 4; ++j) {
        int rl = wm * 64 + mi * 16 + l4 * 4 + j;
        if (mtile * 128 + rl < c) {
          float v1 = acc1[mi][nt][j], v3 = acc3[mi][nt][j];
          float hg = v1 / (1.f + __expf(-v1));
          hh[(long)(p0 + rl) * 1024 + col] = f2bf(hg * v3);
        }
      }
    }
}

// ---------------- MoE grouped GEMM B: BM=128, BN=128, BK=64, counted-vmcnt ----------
__global__ __launch_bounds__(256) void k_moe_b(const short* hh, const short* W2T,
                                               const int* cnt, const int* eoff,
                                               short* mo) {
  int e = blockIdx.z;
  int c = cnt[e];
  int mtile = blockIdx.y;
  if (mtile * 128 >= c) return;
  int p0 = eoff[e] + mtile * 128;
  const short* B = W2T + (long)e * 2048 * 1024;
  int n0 = blockIdx.x * 128;
  __shared__ __align__(16) short As_[2][8192], Bs_[2][8192];
  int tid = threadIdx.x, lane = tid & 63, wave = tid >> 6;
  int l15 = lane & 15, l4 = lane >> 4;
  int wm = wave >> 1, wn = wave & 1;

  const short* bA0 = sb64(hh, 1024, p0, tid);
  const short* bA1 = sb64(hh, 1024, p0, tid + 256);
  const short* bA2 = sb64(hh, 1024, p0, tid + 512);
  const short* bA3 = sb64(hh, 1024, p0, tid + 768);
  const short* bB0 = sb64(B, 1024, n0, tid);
  const short* bB1 = sb64(B, 1024, n0, tid + 256);
  const short* bB2 = sb64(B, 1024, n0, tid + 512);
  const short* bB3 = sb64(B, 1024, n0, tid + 768);

  auto STAGE = [&](int buf, int k0) {
    sissue(As_[buf], bA0, k0, tid, 0);
    sissue(As_[buf], bA1, k0, tid, 256);
    sissue(As_[buf], bA2, k0, tid, 512);
    sissue(As_[buf], bA3, k0, tid, 768);
    sissue(Bs_[buf], bB0, k0, tid, 0);
    sissue(Bs_[buf], bB1, k0, tid, 256);
    sissue(Bs_[buf], bB2, k0, tid, 512);
    sissue(Bs_[buf], bB3, k0, tid, 768);
  };

  floatx4 zero4 = {0.f, 0.f, 0.f, 0.f};
  floatx4 acc[4][4];
#pragma unroll
  for (int i = 0; i < 4; ++i)
#pragma unroll
    for (int j = 0; j < 4; ++j) acc[i][j] = zero4;

  STAGE(0, 0);
  STAGE(1, 64);
  int cur = 0;
  for (int k0 = 0; k0 < 1024; k0 += 64) {
    if (k0 + 128 < 1024) VMCNT(8); else VMCNT(0);
    SBAR();
#pragma unroll
    for (int kh = 0; kh < 2; ++kh) {
      int ch = kh * 4 + l4;
      short8 af[4], bfv[4];
#pragma unroll
      for (int mi = 0; mi < 4; ++mi)
        af[mi] = rd64(As_[cur], wm * 64 + mi * 16 + l15, ch);
#pragma unroll
      for (int nt = 0; nt < 4; ++nt)
        bfv[nt] = rd64(Bs_[cur], wn * 64 + nt * 16 + l15, ch);
#pragma unroll
      for (int mi = 0; mi < 4; ++mi)
#pragma unroll
        for (int nt = 0; nt < 4; ++nt)
          acc[mi][nt] = mfma16(af[mi], bfv[nt], acc[mi][nt]);
    }
    SBAR();
    if (k0 + 128 < 1024) STAGE(cur, k0 + 128);
    cur ^= 1;
  }
#pragma unroll
  for (int mi = 0; mi < 4; ++mi)
#pragma unroll
    for (int nt = 0; nt < 4; ++nt) {
      int col = n0 + wn * 64 + nt * 16 + l15;
#pragma unroll
      for (int j = 0; j < 4; ++j) {
        int rl = wm * 64 + mi * 16 + l4 * 4 + j;
        if (mtile * 128 + rl < c) mo[(long)(p0 + rl) * 2048 + col] = f2bf(acc[mi][nt][j]);
      }
    }
}

// ---------------- flash attention: paired causal tiles, gload_lds staging -----------
DEV int vsw(int r) { return (r ^ (r >> 3)) & 7; }
DEV short8 avread(const short* buf, int row, int c) {
  return *(const short8*)(buf + row * 64 + (((c ^ vsw(row)) & 7) << 3));
}
DEV int aswz(int r, int c) { return r * 64 + (((c ^ ((r ^ (r >> 3)) & 7)) & 7) << 3); }
DEV void glds(short* ldsslot, const short* src) {
  __builtin_amdgcn_global_load_lds(
      (const __attribute__((address_space(1))) void*)src,
      (__attribute__((address_space(3))) void*)ldsslot, 16, 0, 0);
}

__global__ __launch_bounds__(256) void k_attn3(
    const short* qhp, const short* qlp, const short* khp, const short* klp,
    const short* vth2, const short* vtl2, short* oh, short* ol) {
  int xp = blockIdx.x, bh = blockIdx.y;
  int h = bh & 31, b = bh >> 5, kvh = h >> 2;
  int tid = threadIdx.x, wave = tid >> 6, lane = tid & 63;
  int l15 = lane & 15, l4 = lane >> 4;
  int qtA = 15 - xp, qtB = xp;

  __shared__ __align__(16) short Kh[2][4096], Kl[2][4096], Vh[2][4096], Vl[2][4096];
  __shared__ __align__(16) short Ph[4][1024], Pl[4][1024];

  short8 qh[2][2], ql[2][2];
#pragma unroll
  for (int tt = 0; tt < 2; ++tt) {
    int qrow = (tt ? qtB : qtA) * 64 + wave * 16 + l15;
    long qoff = ((long)(b * 1024 + qrow)) * 2048 + h * 64;
    qh[tt][0] = *(const short8*)(qhp + qoff + l4 * 8);
    qh[tt][1] = *(const short8*)(qhp + qoff + 32 + l4 * 8);
    ql[tt][0] = *(const short8*)(qlp + qoff + l4 * 8);
    ql[tt][1] = *(const short8*)(qlp + qoff + 32 + l4 * 8);
  }

  floatx4 zero4 = {0.f, 0.f, 0.f, 0.f};
  floatx4 acco[2][4];
  float mrun[2][4], lrun[2][4];
#pragma unroll
  for (int tt = 0; tt < 2; ++tt)
#pragma unroll
    for (int j = 0; j < 4; ++j) {
      acco[tt][j] = zero4;
      mrun[tt][j] = -1e30f;
      lrun[tt][j] = 0.f;
    }

  const short* khb = khp + ((long)b * 1024) * 512 + kvh * 64;
  const short* klb = klp + ((long)b * 1024) * 512 + kvh * 64;
  const short* vhb = vth2 + (long)(b * 8 + kvh) * 65536;
  const short* vlb = vtl2 + (long)(b * 8 + kvh) * 65536;

  int r0 = tid >> 3, c0 = tid & 7;
  int r1 = r0 + 32;
  const short* kh0 = khb + (long)r0 * 512 + ((c0 ^ vsw(r0)) << 3);
  const short* kh1 = khb + (long)r1 * 512 + ((c0 ^ vsw(r1)) << 3);
  const short* kl0 = klb + (long)r0 * 512 + ((c0 ^ vsw(r0)) << 3);
  const short* kl1 = klb + (long)r1 * 512 + ((c0 ^ vsw(r1)) << 3);
  const short* vh0 = vhb + (long)r0 * 1024 + ((c0 ^ vsw(r0)) << 3);
  const short* vh1 = vhb + (long)r1 * 1024 + ((c0 ^ vsw(r1)) << 3);
  const short* vl0 = vlb + (long)r0 * 1024 + ((c0 ^ vsw(r0)) << 3);
  const short* vl1 = vlb + (long)r1 * 1024 + ((c0 ^ vsw(r1)) << 3);
  int wslot = wave * 512;

  auto STAGE = [&](int buf, int kt) {
    int ko = kt * 32768;
    int vo = kt * 64;
    glds(&Kh[buf][wslot], kh0 + ko);
    glds(&Kh[buf][2048 + wslot], kh1 + ko);
    glds(&Kl[buf][wslot], kl0 + ko);
    glds(&Kl[buf][2048 + wslot], kl1 + ko);
    glds(&Vh[buf][wslot], vh0 + vo);
    glds(&Vh[buf][2048 + wslot], vh1 + vo);
    glds(&Vl[buf][wslot], vl0 + vo);
    glds(&Vl[buf][2048 + wslot], vl1 + vo);
  };

  STAGE(0, 0);
  int cur = 0;
  for (int kt = 0; kt <= qtA; ++kt) {
    __syncthreads();
    if (kt < qtA) STAGE(cur ^ 1, kt + 1);
#pragma unroll
    for (int tt = 0; tt < 2; ++tt) {
      int qtt = tt ? qtB : qtA;
      if (tt == 1 && kt > qtB) continue;
      floatx4 accs[4] = {zero4, zero4, zero4, zero4};
      __builtin_amdgcn_s_setprio(1);
#pragma unroll
      for (int ks = 0; ks < 2; ++ks) {
        short8 qah = qh[tt][ks];
        short8 qal = ql[tt][ks];
#pragma unroll
        for (int nt = 0; nt < 4; ++nt) {
          int kvr = nt * 16 + l15;
          short8 kfh = avread(Kh[cur], kvr, l4 + 4 * ks);
          short8 kfl = avread(Kl[cur], kvr, l4 + 4 * ks);
          accs[nt] = mfma16(qal, kfh, accs[nt]);
          accs[nt] = mfma16(qah, kfl, accs[nt]);
          accs[nt] = mfma16(qah, kfh, accs[nt]);
        }
      }
      __builtin_amdgcn_s_setprio(0);
      if (kt == qtt) {
#pragma unroll
        for (int nt = 0; nt < 4; ++nt)
#pragma unroll
          for (int j = 0; j < 4; ++j) {
            int kvg = nt * 16 + l15;
            int qg = wave * 16 + l4 * 4 + j;
            if (kvg > qg) accs[nt][j] = -1e30f;
          }
      }
      float pj[4][4];
#pragma unroll
      for (int j = 0; j < 4; ++j) {
        float mx = fmaxf(fmaxf(accs[0][j], accs[1][j]), fmaxf(accs[2][j], accs[3][j]));
        mx = fmaxf(mx, __shfl_xor(mx, 1));
        mx = fmaxf(mx, __shfl_xor(mx, 2));
        mx = fmaxf(mx, __shfl_xor(mx, 4));
        mx = fmaxf(mx, __shfl_xor(mx, 8));
        float mnew = fmaxf(mrun[tt][j], mx);
        float alpha = __expf(mrun[tt][j] - mnew);
        float rs = 0.f;
#pragma unroll
        for (int nt = 0; nt < 4; ++nt) {
          float pv = __expf(accs[nt][j] - mnew);
          pj[nt][j] = pv;
          rs += pv;
        }
        rs += __shfl_xor(rs, 1);
        rs += __shfl_xor(rs, 2);
        rs += __shfl_xor(rs, 4);
        rs += __shfl_xor(rs, 8);
        lrun[tt][j] = lrun[tt][j] * alpha + rs;
        mrun[tt][j] = mnew;
        acco[tt][0][j] *= alpha; acco[tt][1][j] *= alpha;
        acco[tt][2][j] *= alpha; acco[tt][3][j] *= alpha;
      }
      short* P = Ph[wave];
      short* P2 = Pl[wave];
#pragma unroll
      for (int nt = 0; nt < 4; ++nt)
#pragma unroll
        for (int j = 0; j < 4; ++j) {
          int rr = l4 * 4 + j, col = nt * 16 + l15;
          float pv = pj[nt][j];
          short hi = f2bf(pv);
          int ad = aswz(rr, col >> 3) + (col & 7);
          P[ad] = hi;
          P2[ad] = f2bf(pv - bf2f(hi));
        }
      asm volatile("s_waitcnt lgkmcnt(0)" ::: "memory");
      __builtin_amdgcn_sched_barrier(0);
      __builtin_amdgcn_s_setprio(1);
#pragma unroll
      for (int ks = 0; ks < 2; ++ks) {
        short8 pah = *(const short8*)(P + aswz(l15, l4 + 4 * ks));
        short8 pal = *(const short8*)(P2 + aswz(l15, l4 + 4 * ks));
#pragma unroll
        for (int nt = 0; nt < 4; ++nt) {
          int dr = nt * 16 + l15;
          short8 vfh = avread(Vh[cur], dr, l4 + 4 * ks);
          short8 vfl = avread(Vl[cur], dr, l4 + 4 * ks);
          acco[tt][nt] = mfma16(pal, vfh, acco[tt][nt]);
          acco[tt][nt] = mfma16(pah, vfl, acco[tt][nt]);
          acco[tt][nt] = mfma16(pah, vfh, acco[tt][nt]);
        }
      }
      __builtin_amdgcn_s_setprio(0);
    }
    cur ^= 1;
  }
#pragma unroll
  for (int tt = 0; tt < 2; ++tt) {
    int qtt = tt ? qtB : qtA;
#pragma unroll
    for (int j = 0; j < 4; ++j) {
      float invl = 1.f / lrun[tt][j];
      int qg = qtt * 64 + wave * 16 + l4 * 4 + j;
      long ooff = ((long)(b * 1024 + qg)) * 2048 + h * 64;
#pragma unroll
      for (int nt = 0; nt < 4; ++nt) {
        float v = acco[tt][nt][j] * invl;
        short hi = f2bf(v);
        oh[ooff + nt * 16 + l15] = hi;
        ol[ooff + nt * 16 + l15] = f2bf(v - bf2f(hi));
      }
    }
  }
}

// ---------------- RMSNorm 2 + MoE gating (fp32 exact path) --------------------------
__global__ __launch_bounds__(256) void k_rmsnorm2_gate(const float* x, const float* w,
                                                       const float* gw, const float* cb,
                                                       short* out, int* sel, float* tw,
                                                       int* cnt) {
  int row = blockIdx.x, tid = threadIdx.x;
  const float* xr = x + (long)row * 2048;
  float4 a = *(const float4*)(xr + tid * 8);
  float4 c = *(const float4*)(xr + tid * 8 + 4);
  float ss = a.x * a.x + a.y * a.y + a.z * a.z + a.w * a.w +
             c.x * c.x + c.y * c.y + c.z * c.z + c.w * c.w;
  ss += __shfl_xor(ss, 1);  ss += __shfl_xor(ss, 2);  ss += __shfl_xor(ss, 4);
  ss += __shfl_xor(ss, 8);  ss += __shfl_xor(ss, 16); ss += __shfl_xor(ss, 32);
  __shared__ float red[4];
  int wave = tid >> 6;
  if ((tid & 63) == 0) red[wave] = ss;
  __syncthreads();
  float tot = red[0] + red[1] + red[2] + red[3];
  float inv = 1.f / sqrtf(tot * (1.f / 2048.f) + 1e-6f);
  float4 w0 = *(const float4*)(w + tid * 8);
  float4 w1 = *(const float4*)(w + tid * 8 + 4);
  float xn[8];
  xn[0] = a.x * inv * w0.x; xn[1] = a.y * inv * w0.y; xn[2] = a.z * inv * w0.z;
  xn[3] = a.w * inv * w0.w; xn[4] = c.x * inv * w1.x; xn[5] = c.y * inv * w1.y;
  xn[6] = c.z * inv * w1.z; xn[7] = c.w * inv * w1.w;
  short8 o;
#pragma unroll
  for (int j = 0; j < 8; ++j) o[j] = f2bf(xn[j]);
  *(short8*)(out + (long)row * 2048 + tid * 8) = o;
  float gp[8] = {0.f, 0.f, 0.f, 0.f, 0.f, 0.f, 0.f, 0.f};
#pragma unroll
  for (int j = 0; j < 8; ++j) {
    const float* g = gw + (long)(tid * 8 + j) * 8;
    float4 g0 = *(const float4*)g;
    float4 g1 = *(const float4*)(g + 4);
    gp[0] += xn[j] * g0.x; gp[1] += xn[j] * g0.y; gp[2] += xn[j] * g0.z; gp[3] += xn[j] * g0.w;
    gp[4] += xn[j] * g1.x; gp[5] += xn[j] * g1.y; gp[6] += xn[j] * g1.z; gp[7] += xn[j] * g1.w;
  }
#pragma unroll
  for (int e = 0; e < 8; ++e) {
    gp[e] += __shfl_xor(gp[e], 1);  gp[e] += __shfl_xor(gp[e], 2);
    gp[e] += __shfl_xor(gp[e], 4);  gp[e] += __shfl_xor(gp[e], 8);
    gp[e] += __shfl_xor(gp[e], 16); gp[e] += __shfl_xor(gp[e], 32);
  }
  __shared__ float gred[4][8];
  __shared__ float srw[8], ssc[8];
  if ((tid & 63) == 0) {
#pragma unroll
    for (int e = 0; e < 8; ++e) gred[wave][e] = gp[e];
  }
  __syncthreads();
  if (tid < 8) {
    float lg = gred[0][tid] + gred[1][tid] + gred[2][tid] + gred[3][tid];
    float rw = 1.f / (1.f + expf(-lg));
    srw[tid] = rw;
    ssc[tid] = rw + cb[tid];
  }
  __syncthreads();
  if (tid == 0) {
    int e0 = 0; float b0 = ssc[0];
    for (int e = 1; e < 8; ++e) if (ssc[e] > b0) { b0 = ssc[e]; e0 = e; }
    int e1 = -1; float b1 = -1e30f;
    for (int e = 0; e < 8; ++e) if (e != e0 && ssc[e] > b1) { b1 = ssc[e]; e1 = e; }
    float t0 = srw[e0], t1 = srw[e1], s = t0 + t1;
    sel[row * 2] = e0; sel[row * 2 + 1] = e1;
    tw[row * 2] = t0 / s; tw[row * 2 + 1] = t1 / s;
    atomicAdd(&cnt[e0], 1);
    atomicAdd(&cnt[e1], 1);
  }
}

// ---------------- routing: merged scan + scatter (single block) ---------------------
__global__ __launch_bounds__(256) void k_scan_scatter(const int* cnt, int* eoff,
                                                      int* fill, const int* sel,
                                                      int* rows, int* pos) {
  if (threadIdx.x == 0) {
    int s = 0;
    for (int e = 0; e < 8; ++e) { eoff[e] = s; s += cnt[e]; }
  }
  __syncthreads();
  for (int base = 0; base < 2048; base += 256) {
    int t = base + threadIdx.x;
    for (int k = 0; k < 2; ++k) {
      int e = sel[t * 2 + k];
      int p = eoff[e] + atomicAdd(&fill[e], 1);
      rows[p] = t;
      pos[t * 2 + k] = p;
    }
  }
}

// ---------------- final combine -----------------------------------------------------
__global__ __launch_bounds__(256) void k_combine(float* out, const short* mo,
                                                 const int* pos, const float* tw) {
  int t = blockIdx.x, tid = threadIdx.x;
  int p0 = pos[t * 2], p1 = pos[t * 2 + 1];
  float w0 = tw[t * 2], w1 = tw[t * 2 + 1];
  float* o = out + (long)t * 2048 + tid * 8;
  short8 m0 = *(const short8*)(mo + (long)p0 * 2048 + tid * 8);
  short8 m1 = *(const short8*)(mo + (long)p1 * 2048 + tid * 8);
  float4 a = *(const float4*)o;
  float4 b = *(const float4*)(o + 4);
  a.x += w0 * bf2f(m0[0]) + w1 * bf2f(m1[0]);
  a.y += w0 * bf2f(m0[1]) + w1 * bf2f(m1[1]);
  a.z += w0 * bf2f(m0[2]) + w1 * bf2f(m1[2]);
  a.w += w0 * bf2f(m0[3]) + w1 * bf2f(m1[3]);
  b.x += w0 * bf2f(m0[4]) + w1 * bf2f(m1[4]);
  b.y += w0 * bf2f(m0[5]) + w1 * bf2f(m1[5]);
  b.z += w0 * bf2f(m0[6]) + w1 * bf2f(m1[6]);
  b.w += w0 * bf2f(m0[7]) + w1 * bf2f(m1[7]);
  *(float4*)o = a;
  *(float4*)(o + 4) = b;
}

// ------------------------------------------------------------------------------------
extern "C" void kernel_launch(void* const* d_in, const int* in_sizes, int n_in,
                              void* d_out, int out_size, void* d_ws, size_t ws_size,
                              hipStream_t stream) {
  const float* x    = (const float*)d_in[0];
  const float* cosb = (const float*)d_in[1];
  const float* sinb = (const float*)d_in[2];
  const float* ln1  = (const float*)d_in[3];
  const float* ln2  = (const float*)d_in[4];
  const float* wq   = (const float*)d_in[5];
  const float* wk   = (const float*)d_in[6];
  const float* wv   = (const float*)d_in[7];
  const float* wo   = (const float*)d_in[8];
  const float* gw   = (const float*)d_in[9];
  const float* cb   = (const float*)d_in[10];
  const float* w1   = (const float*)d_in[11];
  const float* w2   = (const float*)d_in[12];
  const float* w3   = (const float*)d_in[13];
  float* out = (float*)d_out;

  char* p = (char*)d_ws;
  auto take = [&](size_t n) { char* r = p; p += (n + 255) & ~(size_t)255; return r; };
  short* qkvTh = (short*)take(3072L * 2048 * 2);
  short* qkvTl = (short*)take(3072L * 2048 * 2);
  short* woTh  = (short*)take(2048L * 2048 * 2);
  short* woTl  = (short*)take(2048L * 2048 * 2);
  short* w1T   = (short*)take(8L * 1024 * 2048 * 2);
  short* w3T   = (short*)take(8L * 1024 * 2048 * 2);
  short* w2T   = (short*)take(8L * 2048 * 1024 * 2);
  short* hbh   = (short*)take(2048L * 2048 * 2);
  short* hbl   = (short*)take(2048L * 2048 * 2);
  short* qbh   = (short*)take(2048L * 2048 * 2);
  short* qbl   = (short*)take(2048L * 2048 * 2);
  short* kbh   = (short*)take(2048L * 512 * 2);
  short* kbl   = (short*)take(2048L * 512 * 2);
  short* vth   = (short*)take(16L * 64 * 1024 * 2);
  short* vtl   = (short*)take(16L * 64 * 1024 * 2);
  short* aoh   = (short*)take(2048L * 2048 * 2);
  short* aol   = (short*)take(2048L * 2048 * 2);
  short* h2b   = (short*)take(2048L * 2048 * 2);
  short* hhb   = (short*)take(4224L * 1024 * 2);
  short* mob   = (short*)take(4352L * 2048 * 2);
  int* rti     = (int*)take(64 * sizeof(int));
  int* cnt = rti; int* fill = rti + 8; int* eoff = rti + 16;
  int* sel     = (int*)take(2048L * 2 * 4);
  float* twb   = (float*)take(2048L * 2 * 4);
  int* rowsp   = (int*)take(4352L * 4);
  int* posb    = (int*)take(2048L * 2 * 4);
  (void)ws_size; (void)in_sizes; (void)n_in; (void)out_size;

  dim3 B256(256);
  k_trans_pre<<<dim3(3584), B256, 0, stream>>>(wq, wk, wv, qkvTh, qkvTl,
                                               x, ln1, hbh, hbl);
  hipMemsetAsync(rti, 0, 64, stream);

  k_qkv_plus<<<dim3(14080), B256, 0, stream>>>(hbh, hbl, qkvTh, qkvTl, qbh, qbl,
                                               kbh, kbl, vth, vtl, cosb, sinb,
                                               wo, woTh, woTl,
                                               w1, w3, w2, w1T, w3T, w2T);
  k_attn3<<<dim3(8, 64), B256, 0, stream>>>(qbh, qbl, kbh, kbl, vth, vtl, aoh, aol);
  k_gemm_wo<<<dim3(32, 16), B256, 0, stream>>>(aoh, aol, woTh, woTl, x, out);

  k_rmsnorm2_gate<<<dim3(2048), B256, 0, stream>>>(out, ln2, gw, cb, h2b, sel, twb, cnt);
  k_scan_scatter<<<dim3(1), B256, 0, stream>>>(cnt, eoff, fill, sel, rowsp, posb);
  k_moe_a<<<dim3(16, 16, 8), B256, 0, stream>>>(h2b, w1T, w3T, rowsp, cnt, eoff, hhb);
  k_moe_b<<<dim3(16, 16, 8), B256, 0, stream>>>(hhb, w2T, cnt, eoff, mob);
  k_combine<<<dim3(2048), B256, 0, stream>>>(out, mob, posb, twb);
}

// Round 17
// 542.921 us; speedup vs baseline: 1.2437x; 1.2437x over previous
//
#include <hip/hip_runtime.h>
#include <hip/hip_bf16.h>

#define DEV static __device__ __forceinline__

typedef __attribute__((ext_vector_type(8))) short short8;
typedef __attribute__((ext_vector_type(4))) short short4s;
typedef __attribute__((ext_vector_type(8))) __bf16 bf16x8;
typedef __attribute__((ext_vector_type(4))) float floatx4;

DEV short f2bf(float f) {
  unsigned u = __builtin_bit_cast(unsigned, f);
  unsigned r = (u + 0x7fffu + ((u >> 16) & 1u)) >> 16;
  return (short)(unsigned short)r;
}
DEV float bf2f(short s) {
  unsigned u = ((unsigned)(unsigned short)s) << 16;
  return __builtin_bit_cast(float, u);
}
DEV floatx4 mfma16(short8 a, short8 b, floatx4 c) {
  return __builtin_amdgcn_mfma_f32_16x16x32_bf16(
      __builtin_bit_cast(bf16x8, a), __builtin_bit_cast(bf16x8, b), c, 0, 0, 0);
}

#define VMCNT(n) asm volatile("s_waitcnt vmcnt(" #n ")" ::: "memory")
#define SBAR() __builtin_amdgcn_s_barrier()

// ---------------- GEMM staging: [rows][32] bf16 tiles, pre-swizzled source ----------
DEV int sw2(int r) { return (r ^ (r >> 2)) & 3; }

DEV const short* sbase(const short* src, int ld, int row0, int id) {
  int r = id >> 2, cc = id & 3;
  return src + (long)(row0 + r) * ld + ((cc ^ sw2(r)) << 3);
}
DEV void sissue(short* ldsbuf, const short* base, int k0, int tid, int slotbase) {
  int wave = tid >> 6;
  __builtin_amdgcn_global_load_lds(
      (const __attribute__((address_space(1))) void*)(base + k0),
      (__attribute__((address_space(3))) void*)(ldsbuf + (slotbase + wave * 64) * 8),
      16, 0, 0);
}
DEV short8 rdfrag(const short* lds, int row, int l4) {
  return *(const short8*)(lds + row * 32 + ((l4 ^ sw2(row)) << 3));
}

// ---------------- BK=64 staging: [rows][64] bf16 tiles, chunk swizzle c^(r&7) -------
DEV const short* sb64(const short* src, int ld, int row0, int id) {
  int r = id >> 3, c = id & 7;
  return src + (long)(row0 + r) * ld + ((c ^ (r & 7)) << 3);
}
DEV const short* sb64g(const short* src, int ld, const int* rows, int p0, int plim,
                       int id) {
  int r = id >> 3, c = id & 7;
  int pi = p0 + r;
  if (pi > plim) pi = plim;
  return src + (long)rows[pi] * ld + ((c ^ (r & 7)) << 3);
}
DEV short8 rd64(const short* lds, int row, int ch) {
  return *(const short8*)(lds + row * 64 + ((ch ^ (row & 7)) << 3));
}

// ---------------- fused QKV split GEMM: BM=64, BN=128; V written pre-transposed -----
__global__ __launch_bounds__(256) void k_gemm_qkv(
    const short* Ah, const short* Al, const short* Bh, const short* Bl,
    short* qbh, short* qbl, short* kbh, short* kbl, short* vth, short* vtl,
    const float* cs, const float* sn) {
  const int K = 2048;
  __shared__ __align__(16) short AsH[2][2048], AsL[2][2048], BsH[2][4096], BsL[2][4096];
  int tid = threadIdx.x, lane = tid & 63, wave = tid >> 6;
  int l15 = lane & 15, l4 = lane >> 4;
  int wm = wave >> 1, wn = wave & 1;
  int bid = blockIdx.y * 24 + blockIdx.x;
  int swz = (bid & 7) * 96 + (bid >> 3);
  int bx = swz % 24, by = swz / 24;
  int m0 = by * 64, n0 = bx * 128;

  const short* bA_H = sbase(Ah, K, m0, tid);
  const short* bA_L = sbase(Al, K, m0, tid);
  const short* bBH0 = sbase(Bh, K, n0, tid);
  const short* bBH1 = sbase(Bh, K, n0, tid + 256);
  const short* bBL0 = sbase(Bl, K, n0, tid);
  const short* bBL1 = sbase(Bl, K, n0, tid + 256);

  auto STAGE = [&](int buf, int k0) {
    sissue(AsH[buf], bA_H, k0, tid, 0);
    sissue(AsL[buf], bA_L, k0, tid, 0);
    sissue(BsH[buf], bBH0, k0, tid, 0);
    sissue(BsH[buf], bBH1, k0, tid, 256);
    sissue(BsL[buf], bBL0, k0, tid, 0);
    sissue(BsL[buf], bBL1, k0, tid, 256);
  };

  floatx4 zero4 = {0.f, 0.f, 0.f, 0.f};
  floatx4 acc[2][4];
#pragma unroll
  for (int i = 0; i < 2; ++i)
#pragma unroll
    for (int j = 0; j < 4; ++j) acc[i][j] = zero4;

  STAGE(0, 0);
  STAGE(1, 32);
  int cur = 0;
  for (int k0 = 0; k0 < K; k0 += 32) {
    if (k0 + 64 < K) VMCNT(6); else VMCNT(0);
    SBAR();
    short8 ah[2], al[2], bh2[4], bl2[4];
#pragma unroll
    for (int mi = 0; mi < 2; ++mi) {
      ah[mi] = rdfrag(AsH[cur], wm * 32 + mi * 16 + l15, l4);
      al[mi] = rdfrag(AsL[cur], wm * 32 + mi * 16 + l15, l4);
    }
#pragma unroll
    for (int nt = 0; nt < 4; ++nt) {
      bh2[nt] = rdfrag(BsH[cur], wn * 64 + nt * 16 + l15, l4);
      bl2[nt] = rdfrag(BsL[cur], wn * 64 + nt * 16 + l15, l4);
    }
#pragma unroll
    for (int mi = 0; mi < 2; ++mi)
#pragma unroll
      for (int nt = 0; nt < 4; ++nt) {
        acc[mi][nt] = mfma16(al[mi], bh2[nt], acc[mi][nt]);
        acc[mi][nt] = mfma16(ah[mi], bl2[nt], acc[mi][nt]);
        acc[mi][nt] = mfma16(ah[mi], bh2[nt], acc[mi][nt]);
      }
    SBAR();
    if (k0 + 64 < K) STAGE(cur, k0 + 64);
    cur ^= 1;
  }

  int p = (n0 >> 6) + wn;  // 64-col panel = one head
  bool isq = p < 32, isk = (!isq) && p < 40;
  if (isq || isk) {
#pragma unroll
    for (int mi = 0; mi < 2; ++mi)
#pragma unroll
      for (int ntp = 0; ntp < 2; ++ntp)
#pragma unroll
        for (int j = 0; j < 4; ++j) {
          int row = m0 + wm * 32 + mi * 16 + l4 * 4 + j;
          int d = ntp * 16 + l15;
          float x0 = acc[mi][ntp][j], x1 = acc[mi][ntp + 2][j];
          float c0 = cs[row * 64 + d], c1 = cs[row * 64 + d + 32];
          float s0 = sn[row * 64 + d], s1 = sn[row * 64 + d + 32];
          float y0 = x0 * c0 - x1 * s0;
          float y1 = x1 * c1 + x0 * s1;
          if (isq) { y0 *= 0.125f; y1 *= 0.125f; }
          acc[mi][ntp][j] = y0;
          acc[mi][ntp + 2][j] = y1;
        }
    short* Ch; short* Cl; int ldc, coff;
    if (isq) { Ch = qbh; Cl = qbl; ldc = 2048; coff = p * 64; }
    else     { Ch = kbh; Cl = kbl; ldc = 512;  coff = (p - 32) * 64; }
#pragma unroll
    for (int mi = 0; mi < 2; ++mi)
#pragma unroll
      for (int nt = 0; nt < 4; ++nt) {
        int row = m0 + wm * 32 + mi * 16 + l4 * 4;
        int col = coff + nt * 16 + l15;
#pragma unroll
        for (int j = 0; j < 4; ++j) {
          float v = acc[mi][nt][j];
          long ix = (long)(row + j) * ldc + col;
          short hi = f2bf(v);
          Ch[ix] = hi;
          Cl[ix] = f2bf(v - bf2f(hi));
        }
      }
  } else {
    // V panel: write directly transposed vt[b*8+kvh][d=64][t=1024]
    int kvh = p - 40;
#pragma unroll
    for (int mi = 0; mi < 2; ++mi)
#pragma unroll
      for (int nt = 0; nt < 4; ++nt) {
        int row0 = m0 + wm * 32 + mi * 16 + l4 * 4;
        int d = nt * 16 + l15;
        int bb = row0 >> 10, tt = row0 & 1023;
        long base = ((long)(bb * 8 + kvh)) * 65536 + (long)d * 1024 + tt;
        short4s hv, lv;
#pragma unroll
        for (int j = 0; j < 4; ++j) {
          float v = acc[mi][nt][j];
          short hi = f2bf(v);
          hv[j] = hi;
          lv[j] = f2bf(v - bf2f(hi));
        }
        *(short4s*)(vth + base) = hv;
        *(short4s*)(vtl + base) = lv;
      }
  }
}

// ---------------- WO split GEMM + residual: BM=128, BN=64, counted-vmcnt, XCD swz ---
__global__ __launch_bounds__(256) void k_gemm_wo(const short* Ah, const short* Al,
                                                 const short* Bh, const short* Bl,
                                                 const float* resid, float* out) {
  const int K = 2048;
  __shared__ __align__(16) short AsH[2][4096], AsL[2][4096], BsH[2][2048], BsL[2][2048];
  int tid = threadIdx.x, lane = tid & 63, wave = tid >> 6;
  int l15 = lane & 15, l4 = lane >> 4;
  int bid = blockIdx.y * 32 + blockIdx.x;
  int swz = (bid & 7) * 64 + (bid >> 3);
  int bx = swz % 32, by = swz / 32;
  int m0 = by * 128, n0 = bx * 64;

  const short* bAH0 = sbase(Ah, K, m0, tid);
  const short* bAH1 = sbase(Ah, K, m0, tid + 256);
  const short* bAL0 = sbase(Al, K, m0, tid);
  const short* bAL1 = sbase(Al, K, m0, tid + 256);
  const short* bBH0 = sbase(Bh, K, n0, tid);
  const short* bBL0 = sbase(Bl, K, n0, tid);

  auto STAGE = [&](int buf, int k0) {
    sissue(AsH[buf], bAH0, k0, tid, 0);
    sissue(AsH[buf], bAH1, k0, tid, 256);
    sissue(AsL[buf], bAL0, k0, tid, 0);
    sissue(AsL[buf], bAL1, k0, tid, 256);
    sissue(BsH[buf], bBH0, k0, tid, 0);
    sissue(BsL[buf], bBL0, k0, tid, 0);
  };

  floatx4 zero4 = {0.f, 0.f, 0.f, 0.f};
  floatx4 acc[2][4];
#pragma unroll
  for (int i = 0; i < 2; ++i)
#pragma unroll
    for (int j = 0; j < 4; ++j) acc[i][j] = zero4;

  STAGE(0, 0);
  STAGE(1, 32);
  int cur = 0;
  for (int k0 = 0; k0 < K; k0 += 32) {
    if (k0 + 64 < K) VMCNT(6); else VMCNT(0);
    SBAR();
    short8 ah[2], al[2], bh2[4], bl2[4];
#pragma unroll
    for (int mi = 0; mi < 2; ++mi) {
      ah[mi] = rdfrag(AsH[cur], wave * 32 + mi * 16 + l15, l4);
      al[mi] = rdfrag(AsL[cur], wave * 32 + mi * 16 + l15, l4);
    }
#pragma unroll
    for (int nt = 0; nt < 4; ++nt) {
      bh2[nt] = rdfrag(BsH[cur], nt * 16 + l15, l4);
      bl2[nt] = rdfrag(BsL[cur], nt * 16 + l15, l4);
    }
#pragma unroll
    for (int mi = 0; mi < 2; ++mi)
#pragma unroll
      for (int nt = 0; nt < 4; ++nt) {
        acc[mi][nt] = mfma16(al[mi], bh2[nt], acc[mi][nt]);
        acc[mi][nt] = mfma16(ah[mi], bl2[nt], acc[mi][nt]);
        acc[mi][nt] = mfma16(ah[mi], bh2[nt], acc[mi][nt]);
      }
    SBAR();
    if (k0 + 64 < K) STAGE(cur, k0 + 64);
    cur ^= 1;
  }
#pragma unroll
  for (int mi = 0; mi < 2; ++mi)
#pragma unroll
    for (int nt = 0; nt < 4; ++nt) {
      int row = m0 + wave * 32 + mi * 16 + l4 * 4;
      int col = n0 + nt * 16 + l15;
#pragma unroll
      for (int j = 0; j < 4; ++j) {
        long ix = (long)(row + j) * 2048 + col;
        out[ix] = resid[ix] + acc[mi][nt][j];
      }
    }
}

// ---------------- MoE grouped GEMM A: BM=128, BN=64, BK=64, counted-vmcnt -----------
__global__ __launch_bounds__(256) void k_moe_a(const short* X, const short* W1T,
                                               const short* W3T, const int* rows,
                                               const int* cnt, const int* eoff,
                                               short* hh) {
  int e = blockIdx.z;
  int c = cnt[e];
  int mtile = blockIdx.y;
  if (mtile * 128 >= c) return;
  int p0 = eoff[e] + mtile * 128;
  int plim = eoff[e] + c - 1;
  const short* B1 = W1T + (long)e * 1024 * 2048;
  const short* B3 = W3T + (long)e * 1024 * 2048;
  int n0 = blockIdx.x * 64;
  __shared__ __align__(16) short As_[2][8192], B1s[2][4096], B3s[2][4096];
  int tid = threadIdx.x, lane = tid & 63, wave = tid >> 6;
  int l15 = lane & 15, l4 = lane >> 4;
  int wm = wave >> 1, wn = wave & 1;

  const short* bA0 = sb64g(X, 2048, rows, p0, plim, tid);
  const short* bA1 = sb64g(X, 2048, rows, p0, plim, tid + 256);
  const short* bA2 = sb64g(X, 2048, rows, p0, plim, tid + 512);
  const short* bA3 = sb64g(X, 2048, rows, p0, plim, tid + 768);
  const short* bB1_0 = sb64(B1, 2048, n0, tid);
  const short* bB1_1 = sb64(B1, 2048, n0, tid + 256);
  const short* bB3_0 = sb64(B3, 2048, n0, tid);
  const short* bB3_1 = sb64(B3, 2048, n0, tid + 256);

  auto STAGE = [&](int buf, int k0) {
    sissue(As_[buf], bA0, k0, tid, 0);
    sissue(As_[buf], bA1, k0, tid, 256);
    sissue(As_[buf], bA2, k0, tid, 512);
    sissue(As_[buf], bA3, k0, tid, 768);
    sissue(B1s[buf], bB1_0, k0, tid, 0);
    sissue(B1s[buf], bB1_1, k0, tid, 256);
    sissue(B3s[buf], bB3_0, k0, tid, 0);
    sissue(B3s[buf], bB3_1, k0, tid, 256);
  };

  floatx4 zero4 = {0.f, 0.f, 0.f, 0.f};
  floatx4 acc1[4][2], acc3[4][2];
#pragma unroll
  for (int i = 0; i < 4; ++i)
#pragma unroll
    for (int j = 0; j < 2; ++j) { acc1[i][j] = zero4; acc3[i][j] = zero4; }

  STAGE(0, 0);
  STAGE(1, 64);
  int cur = 0;
  for (int k0 = 0; k0 < 2048; k0 += 64) {
    if (k0 + 128 < 2048) VMCNT(8); else VMCNT(0);
    SBAR();
#pragma unroll
    for (int kh = 0; kh < 2; ++kh) {
      int ch = kh * 4 + l4;
      short8 af[4], b1f[2], b3f[2];
#pragma unroll
      for (int mi = 0; mi < 4; ++mi)
        af[mi] = rd64(As_[cur], wm * 64 + mi * 16 + l15, ch);
#pragma unroll
      for (int nt = 0; nt < 2; ++nt) {
        b1f[nt] = rd64(B1s[cur], wn * 32 + nt * 16 + l15, ch);
        b3f[nt] = rd64(B3s[cur], wn * 32 + nt * 16 + l15, ch);
      }
#pragma unroll
      for (int mi = 0; mi < 4; ++mi)
#pragma unroll
        for (int nt = 0; nt < 2; ++nt) {
          acc1[mi][nt] = mfma16(af[mi], b1f[nt], acc1[mi][nt]);
          acc3[mi][nt] = mfma16(af[mi], b3f[nt], acc3[mi][nt]);
        }
    }
    SBAR();
    if (k0 + 128 < 2048) STAGE(cur, k0 + 128);
    cur ^= 1;
  }
#pragma unroll
  for (int mi = 0; mi < 4; ++mi)
#pragma unroll
    for (int nt = 0; nt < 2; ++nt) {
      int col = n0 + wn * 32 + nt * 16 + l15;
#pragma unroll
      for (int j = 0; j < 4; ++j) {
        int rl = wm * 64 + mi * 16 + l4 * 4 + j;
        if (mtile * 128 + rl < c) {
          float v1 = acc1[mi][nt][j], v3 = acc3[mi][nt][j];
          float hg = v1 / (1.f + __expf(-v1));
          hh[(long)(p0 + rl) * 1024 + col] = f2bf(hg * v3);
        }
      }
    }
}

// ---------------- MoE grouped GEMM B: BM=128, BN=128, BK=64, counted-vmcnt ----------
__global__ __launch_bounds__(256) void k_moe_b(const short* hh, const short* W2T,
                                               const int* cnt, const int* eoff,
                                               short* mo) {
  int e = blockIdx.z;
  int c = cnt[e];
  int mtile = blockIdx.y;
  if (mtile * 128 >= c) return;
  int p0 = eoff[e] + mtile * 128;
  const short* B = W2T + (long)e * 2048 * 1024;
  int n0 = blockIdx.x * 128;
  __shared__ __align__(16) short As_[2][8192], Bs_[2][8192];
  int tid = threadIdx.x, lane = tid & 63, wave = tid >> 6;
  int l15 = lane & 15, l4 = lane >> 4;
  int wm = wave >> 1, wn = wave & 1;

  const short* bA0 = sb64(hh, 1024, p0, tid);
  const short* bA1 = sb64(hh, 1024, p0, tid + 256);
  const short* bA2 = sb64(hh, 1024, p0, tid + 512);
  const short* bA3 = sb64(hh, 1024, p0, tid + 768);
  const short* bB0 = sb64(B, 1024, n0, tid);
  const short* bB1 = sb64(B, 1024, n0, tid + 256);
  const short* bB2 = sb64(B, 1024, n0, tid + 512);
  const short* bB3 = sb64(B, 1024, n0, tid + 768);

  auto STAGE = [&](int buf, int k0) {
    sissue(As_[buf], bA0, k0, tid, 0);
    sissue(As_[buf], bA1, k0, tid, 256);
    sissue(As_[buf], bA2, k0, tid, 512);
    sissue(As_[buf], bA3, k0, tid, 768);
    sissue(Bs_[buf], bB0, k0, tid, 0);
    sissue(Bs_[buf], bB1, k0, tid, 256);
    sissue(Bs_[buf], bB2, k0, tid, 512);
    sissue(Bs_[buf], bB3, k0, tid, 768);
  };

  floatx4 zero4 = {0.f, 0.f, 0.f, 0.f};
  floatx4 acc[4][4];
#pragma unroll
  for (int i = 0; i < 4; ++i)
#pragma unroll
    for (int j = 0; j < 4; ++j) acc[i][j] = zero4;

  STAGE(0, 0);
  STAGE(1, 64);
  int cur = 0;
  for (int k0 = 0; k0 < 1024; k0 += 64) {
    if (k0 + 128 < 1024) VMCNT(8); else VMCNT(0);
    SBAR();
#pragma unroll
    for (int kh = 0; kh < 2; ++kh) {
      int ch = kh * 4 + l4;
      short8 af[4], bfv[4];
#pragma unroll
      for (int mi = 0; mi < 4; ++mi)
        af[mi] = rd64(As_[cur], wm * 64 + mi * 16 + l15, ch);
#pragma unroll
      for (int nt = 0; nt < 4; ++nt)
        bfv[nt] = rd64(Bs_[cur], wn * 64 + nt * 16 + l15, ch);
#pragma unroll
      for (int mi = 0; mi < 4; ++mi)
#pragma unroll
        for (int nt = 0; nt < 4; ++nt)
          acc[mi][nt] = mfma16(af[mi], bfv[nt], acc[mi][nt]);
    }
    SBAR();
    if (k0 + 128 < 1024) STAGE(cur, k0 + 128);
    cur ^= 1;
  }
#pragma unroll
  for (int mi = 0; mi < 4; ++mi)
#pragma unroll
    for (int nt = 0; nt < 4; ++nt) {
      int col = n0 + wn * 64 + nt * 16 + l15;
#pragma unroll
      for (int j = 0; j < 4; ++j) {
        int rl = wm * 64 + mi * 16 + l4 * 4 + j;
        if (mtile * 128 + rl < c) mo[(long)(p0 + rl) * 2048 + col] = f2bf(acc[mi][nt][j]);
      }
    }
}

// ---------------- flash attention: paired causal tiles, gload_lds staging -----------
DEV int vsw(int r) { return (r ^ (r >> 3)) & 7; }
DEV short8 avread(const short* buf, int row, int c) {
  return *(const short8*)(buf + row * 64 + (((c ^ vsw(row)) & 7) << 3));
}
DEV int aswz(int r, int c) { return r * 64 + (((c ^ ((r ^ (r >> 3)) & 7)) & 7) << 3); }
DEV void glds(short* ldsslot, const short* src) {
  __builtin_amdgcn_global_load_lds(
      (const __attribute__((address_space(1))) void*)src,
      (__attribute__((address_space(3))) void*)ldsslot, 16, 0, 0);
}

__global__ __launch_bounds__(256) void k_attn3(
    const short* qhp, const short* qlp, const short* khp, const short* klp,
    const short* vth2, const short* vtl2, short* oh, short* ol) {
  int xp = blockIdx.x, bh = blockIdx.y;
  int h = bh & 31, b = bh >> 5, kvh = h >> 2;
  int tid = threadIdx.x, wave = tid >> 6, lane = tid & 63;
  int l15 = lane & 15, l4 = lane >> 4;
  int qtA = 15 - xp, qtB = xp;

  __shared__ __align__(16) short Kh[2][4096], Kl[2][4096], Vh[2][4096], Vl[2][4096];
  __shared__ __align__(16) short Ph[4][1024], Pl[4][1024];

  short8 qh[2][2], ql[2][2];
#pragma unroll
  for (int tt = 0; tt < 2; ++tt) {
    int qrow = (tt ? qtB : qtA) * 64 + wave * 16 + l15;
    long qoff = ((long)(b * 1024 + qrow)) * 2048 + h * 64;
    qh[tt][0] = *(const short8*)(qhp + qoff + l4 * 8);
    qh[tt][1] = *(const short8*)(qhp + qoff + 32 + l4 * 8);
    ql[tt][0] = *(const short8*)(qlp + qoff + l4 * 8);
    ql[tt][1] = *(const short8*)(qlp + qoff + 32 + l4 * 8);
  }

  floatx4 zero4 = {0.f, 0.f, 0.f, 0.f};
  floatx4 acco[2][4];
  float mrun[2][4], lrun[2][4];
#pragma unroll
  for (int tt = 0; tt < 2; ++tt)
#pragma unroll
    for (int j = 0; j < 4; ++j) {
      acco[tt][j] = zero4;
      mrun[tt][j] = -1e30f;
      lrun[tt][j] = 0.f;
    }

  const short* khb = khp + ((long)b * 1024) * 512 + kvh * 64;
  const short* klb = klp + ((long)b * 1024) * 512 + kvh * 64;
  const short* vhb = vth2 + (long)(b * 8 + kvh) * 65536;
  const short* vlb = vtl2 + (long)(b * 8 + kvh) * 65536;

  int r0 = tid >> 3, c0 = tid & 7;
  int r1 = r0 + 32;
  const short* kh0 = khb + (long)r0 * 512 + ((c0 ^ vsw(r0)) << 3);
  const short* kh1 = khb + (long)r1 * 512 + ((c0 ^ vsw(r1)) << 3);
  const short* kl0 = klb + (long)r0 * 512 + ((c0 ^ vsw(r0)) << 3);
  const short* kl1 = klb + (long)r1 * 512 + ((c0 ^ vsw(r1)) << 3);
  const short* vh0 = vhb + (long)r0 * 1024 + ((c0 ^ vsw(r0)) << 3);
  const short* vh1 = vhb + (long)r1 * 1024 + ((c0 ^ vsw(r1)) << 3);
  const short* vl0 = vlb + (long)r0 * 1024 + ((c0 ^ vsw(r0)) << 3);
  const short* vl1 = vlb + (long)r1 * 1024 + ((c0 ^ vsw(r1)) << 3);
  int wslot = wave * 512;

  auto STAGE = [&](int buf, int kt) {
    int ko = kt * 32768;
    int vo = kt * 64;
    glds(&Kh[buf][wslot], kh0 + ko);
    glds(&Kh[buf][2048 + wslot], kh1 + ko);
    glds(&Kl[buf][wslot], kl0 + ko);
    glds(&Kl[buf][2048 + wslot], kl1 + ko);
    glds(&Vh[buf][wslot], vh0 + vo);
    glds(&Vh[buf][2048 + wslot], vh1 + vo);
    glds(&Vl[buf][wslot], vl0 + vo);
    glds(&Vl[buf][2048 + wslot], vl1 + vo);
  };

  STAGE(0, 0);
  int cur = 0;
  for (int kt = 0; kt <= qtA; ++kt) {
    __syncthreads();
    if (kt < qtA) STAGE(cur ^ 1, kt + 1);
#pragma unroll
    for (int tt = 0; tt < 2; ++tt) {
      int qtt = tt ? qtB : qtA;
      if (tt == 1 && kt > qtB) continue;
      floatx4 accs[4] = {zero4, zero4, zero4, zero4};
      __builtin_amdgcn_s_setprio(1);
#pragma unroll
      for (int ks = 0; ks < 2; ++ks) {
        short8 qah = qh[tt][ks];
        short8 qal = ql[tt][ks];
#pragma unroll
        for (int nt = 0; nt < 4; ++nt) {
          int kvr = nt * 16 + l15;
          short8 kfh = avread(Kh[cur], kvr, l4 + 4 * ks);
          short8 kfl = avread(Kl[cur], kvr, l4 + 4 * ks);
          accs[nt] = mfma16(qal, kfh, accs[nt]);
          accs[nt] = mfma16(qah, kfl, accs[nt]);
          accs[nt] = mfma16(qah, kfh, accs[nt]);
        }
      }
      __builtin_amdgcn_s_setprio(0);
      if (kt == qtt) {
#pragma unroll
        for (int nt = 0; nt < 4; ++nt)
#pragma unroll
          for (int j = 0; j < 4; ++j) {
            int kvg = nt * 16 + l15;
            int qg = wave * 16 + l4 * 4 + j;
            if (kvg > qg) accs[nt][j] = -1e30f;
          }
      }
      float pj[4][4];
#pragma unroll
      for (int j = 0; j < 4; ++j) {
        float mx = fmaxf(fmaxf(accs[0][j], accs[1][j]), fmaxf(accs[2][j], accs[3][j]));
        mx = fmaxf(mx, __shfl_xor(mx, 1));
        mx = fmaxf(mx, __shfl_xor(mx, 2));
        mx = fmaxf(mx, __shfl_xor(mx, 4));
        mx = fmaxf(mx, __shfl_xor(mx, 8));
        float mnew = fmaxf(mrun[tt][j], mx);
        float alpha = __expf(mrun[tt][j] - mnew);
        float rs = 0.f;
#pragma unroll
        for (int nt = 0; nt < 4; ++nt) {
          float pv = __expf(accs[nt][j] - mnew);
          pj[nt][j] = pv;
          rs += pv;
        }
        rs += __shfl_xor(rs, 1);
        rs += __shfl_xor(rs, 2);
        rs += __shfl_xor(rs, 4);
        rs += __shfl_xor(rs, 8);
        lrun[tt][j] = lrun[tt][j] * alpha + rs;
        mrun[tt][j] = mnew;
        acco[tt][0][j] *= alpha; acco[tt][1][j] *= alpha;
        acco[tt][2][j] *= alpha; acco[tt][3][j] *= alpha;
      }
      short* P = Ph[wave];
      short* P2 = Pl[wave];
#pragma unroll
      for (int nt = 0; nt < 4; ++nt)
#pragma unroll
        for (int j = 0; j < 4; ++j) {
          int rr = l4 * 4 + j, col = nt * 16 + l15;
          float pv = pj[nt][j];
          short hi = f2bf(pv);
          int ad = aswz(rr, col >> 3) + (col & 7);
          P[ad] = hi;
          P2[ad] = f2bf(pv - bf2f(hi));
        }
      asm volatile("s_waitcnt lgkmcnt(0)" ::: "memory");
      __builtin_amdgcn_sched_barrier(0);
      __builtin_amdgcn_s_setprio(1);
#pragma unroll
      for (int ks = 0; ks < 2; ++ks) {
        short8 pah = *(const short8*)(P + aswz(l15, l4 + 4 * ks));
        short8 pal = *(const short8*)(P2 + aswz(l15, l4 + 4 * ks));
#pragma unroll
        for (int nt = 0; nt < 4; ++nt) {
          int dr = nt * 16 + l15;
          short8 vfh = avread(Vh[cur], dr, l4 + 4 * ks);
          short8 vfl = avread(Vl[cur], dr, l4 + 4 * ks);
          acco[tt][nt] = mfma16(pal, vfh, acco[tt][nt]);
          acco[tt][nt] = mfma16(pah, vfl, acco[tt][nt]);
          acco[tt][nt] = mfma16(pah, vfh, acco[tt][nt]);
        }
      }
      __builtin_amdgcn_s_setprio(0);
    }
    cur ^= 1;
  }
#pragma unroll
  for (int tt = 0; tt < 2; ++tt) {
    int qtt = tt ? qtB : qtA;
#pragma unroll
    for (int j = 0; j < 4; ++j) {
      float invl = 1.f / lrun[tt][j];
      int qg = qtt * 64 + wave * 16 + l4 * 4 + j;
      long ooff = ((long)(b * 1024 + qg)) * 2048 + h * 64;
#pragma unroll
      for (int nt = 0; nt < 4; ++nt) {
        float v = acco[tt][nt][j] * invl;
        short hi = f2bf(v);
        oh[ooff + nt * 16 + l15] = hi;
        ol[ooff + nt * 16 + l15] = f2bf(v - bf2f(hi));
      }
    }
  }
}

// ---------------- merged weight transpose+convert + rmsnorm1 (one launch) -----------
DEV void trans_load(const float* src, int N, int n0, int k0, float (*t)[65], int tid) {
  int r = tid >> 2, cq = tid & 3;
  const float* s = src + (long)(k0 + r) * N + n0 + cq * 16;
#pragma unroll
  for (int i = 0; i < 4; ++i) {
    float4 v = *(const float4*)(s + i * 4);
    t[r][cq * 16 + i * 4 + 0] = v.x;
    t[r][cq * 16 + i * 4 + 1] = v.y;
    t[r][cq * 16 + i * 4 + 2] = v.z;
    t[r][cq * 16 + i * 4 + 3] = v.w;
  }
}

DEV void trans_tile1(const float* src, short* dst, int N, int K, int n0, int k0,
                     float (*t)[65]) {
  int tid = threadIdx.x;
  trans_load(src, N, n0, k0, t, tid);
  __syncthreads();
  int n = tid >> 2, kc = tid & 3;
#pragma unroll
  for (int ii = 0; ii < 2; ++ii) {
    short8 o;
#pragma unroll
    for (int j = 0; j < 8; ++j) o[j] = f2bf(t[kc * 16 + ii * 8 + j][n]);
    *(short8*)(dst + (long)(n0 + n) * K + k0 + kc * 16 + ii * 8) = o;
  }
}

DEV void trans_tile2(const float* src, short* dh, short* dl, int N, int K, int n0,
                     int k0, float (*t)[65]) {
  int tid = threadIdx.x;
  trans_load(src, N, n0, k0, t, tid);
  __syncthreads();
  int n = tid >> 2, kc = tid & 3;
#pragma unroll
  for (int ii = 0; ii < 2; ++ii) {
    short8 ohv, olv;
#pragma unroll
    for (int j = 0; j < 8; ++j) {
      float v = t[kc * 16 + ii * 8 + j][n];
      short hi = f2bf(v);
      ohv[j] = hi;
      olv[j] = f2bf(v - bf2f(hi));
    }
    *(short8*)(dh + (long)(n0 + n) * K + k0 + kc * 16 + ii * 8) = ohv;
    *(short8*)(dl + (long)(n0 + n) * K + k0 + kc * 16 + ii * 8) = olv;
  }
}

__global__ __launch_bounds__(256) void k_trans_all(
    const float* wq, const float* wk, const float* wv, const float* wo,
    const float* w1, const float* w3, const float* w2,
    short* qkvTh, short* qkvTl, short* woTh, short* woTl,
    short* w1T, short* w3T, short* w2T,
    const float* x, const float* ln1, short* hbh, short* hbl) {
  __shared__ float t[64][65];
  __shared__ float red[4];
  int bid = blockIdx.x;
  if (bid < 2560) {
    int xx = bid % 80, kt = bid / 80;
    const float* src; short* dh; short* dl; int N, n0;
    if (xx < 32)      { src = wq; dh = qkvTh; dl = qkvTl; N = 2048; n0 = xx * 64; }
    else if (xx < 40) { src = wk; dh = qkvTh + 2048L * 2048; dl = qkvTl + 2048L * 2048;
                        N = 512; n0 = (xx - 32) * 64; }
    else if (xx < 48) { src = wv; dh = qkvTh + 2560L * 2048; dl = qkvTl + 2560L * 2048;
                        N = 512; n0 = (xx - 40) * 64; }
    else              { src = wo; dh = woTh; dl = woTl; N = 2048; n0 = (xx - 48) * 64; }
    trans_tile2(src, dh, dl, N, 2048, n0, kt * 64, t);
  } else if (bid < 10752) {
    int i = bid - 2560;
    int xx = i % 256, kt = i / 256;
    const float* src; short* dst; int n0;
    if (xx < 128) { int e = xx >> 4; src = w1 + (long)e * 2048 * 1024;
                    dst = w1T + (long)e * 1024 * 2048; n0 = (xx & 15) * 64; }
    else          { int x2 = xx - 128, e = x2 >> 4; src = w3 + (long)e * 2048 * 1024;
                    dst = w3T + (long)e * 1024 * 2048; n0 = (x2 & 15) * 64; }
    trans_tile1(src, dst, 1024, 2048, n0, kt * 64, t);
  } else if (bid < 14848) {
    int i = bid - 10752;
    int xx = i % 256, kt = i / 256;
    int e = xx >> 5, ntb = xx & 31;
    trans_tile1(w2 + (long)e * 1024 * 2048, w2T + (long)e * 2048 * 1024,
                2048, 1024, ntb * 64, kt * 64, t);
  } else {
    // rmsnorm1 rows
    int row = bid - 14848, tid = threadIdx.x;
    const float* xr = x + (long)row * 2048;
    float4 a = *(const float4*)(xr + tid * 8);
    float4 c = *(const float4*)(xr + tid * 8 + 4);
    float ss = a.x * a.x + a.y * a.y + a.z * a.z + a.w * a.w +
               c.x * c.x + c.y * c.y + c.z * c.z + c.w * c.w;
    ss += __shfl_xor(ss, 1);  ss += __shfl_xor(ss, 2);  ss += __shfl_xor(ss, 4);
    ss += __shfl_xor(ss, 8);  ss += __shfl_xor(ss, 16); ss += __shfl_xor(ss, 32);
    int wave = tid >> 6;
    if ((tid & 63) == 0) red[wave] = ss;
    __syncthreads();
    float tot = red[0] + red[1] + red[2] + red[3];
    float inv = 1.f / sqrtf(tot * (1.f / 2048.f) + 1e-6f);
    float4 w0 = *(const float4*)(ln1 + tid * 8);
    float4 w1v = *(const float4*)(ln1 + tid * 8 + 4);
    float xv[8] = {a.x * w0.x, a.y * w0.y, a.z * w0.z, a.w * w0.w,
                   c.x * w1v.x, c.y * w1v.y, c.z * w1v.z, c.w * w1v.w};
    short8 ohv, olv;
#pragma unroll
    for (int j = 0; j < 8; ++j) {
      float v = xv[j] * inv;
      short hi = f2bf(v);
      ohv[j] = hi;
      olv[j] = f2bf(v - bf2f(hi));
    }
    *(short8*)(hbh + (long)row * 2048 + tid * 8) = ohv;
    *(short8*)(hbl + (long)row * 2048 + tid * 8) = olv;
  }
}

// ---------------- RMSNorm 2 + MoE gating (fp32 exact path) --------------------------
__global__ __launch_bounds__(256) void k_rmsnorm2_gate(const float* x, const float* w,
                                                       const float* gw, const float* cb,
                                                       short* out, int* sel, float* tw,
                                                       int* cnt) {
  int row = blockIdx.x, tid = threadIdx.x;
  const float* xr = x + (long)row * 2048;
  float4 a = *(const float4*)(xr + tid * 8);
  float4 c = *(const float4*)(xr + tid * 8 + 4);
  float ss = a.x * a.x + a.y * a.y + a.z * a.z + a.w * a.w +
             c.x * c.x + c.y * c.y + c.z * c.z + c.w * c.w;
  ss += __shfl_xor(ss, 1);  ss += __shfl_xor(ss, 2);  ss += __shfl_xor(ss, 4);
  ss += __shfl_xor(ss, 8);  ss += __shfl_xor(ss, 16); ss += __shfl_xor(ss, 32);
  __shared__ float red[4];
  int wave = tid >> 6;
  if ((tid & 63) == 0) red[wave] = ss;
  __syncthreads();
  float tot = red[0] + red[1] + red[2] + red[3];
  float inv = 1.f / sqrtf(tot * (1.f / 2048.f) + 1e-6f);
  float4 w0 = *(const float4*)(w + tid * 8);
  float4 w1 = *(const float4*)(w + tid * 8 + 4);
  float xn[8];
  xn[0] = a.x * inv * w0.x; xn[1] = a.y * inv * w0.y; xn[2] = a.z * inv * w0.z;
  xn[3] = a.w * inv * w0.w; xn[4] = c.x * inv * w1.x; xn[5] = c.y * inv * w1.y;
  xn[6] = c.z * inv * w1.z; xn[7] = c.w * inv * w1.w;
  short8 o;
#pragma unroll
  for (int j = 0; j < 8; ++j) o[j] = f2bf(xn[j]);
  *(short8*)(out + (long)row * 2048 + tid * 8) = o;
  float gp[8] = {0.f, 0.f, 0.f, 0.f, 0.f, 0.f, 0.f, 0.f};
#pragma unroll
  for (int j = 0; j < 8; ++j) {
    const float* g = gw + (long)(tid * 8 + j) * 8;
    float4 g0 = *(const float4*)g;
    float4 g1 = *(const float4*)(g + 4);
    gp[0] += xn[j] * g0.x; gp[1] += xn[j] * g0.y; gp[2] += xn[j] * g0.z; gp[3] += xn[j] * g0.w;
    gp[4] += xn[j] * g1.x; gp[5] += xn[j] * g1.y; gp[6] += xn[j] * g1.z; gp[7] += xn[j] * g1.w;
  }
#pragma unroll
  for (int e = 0; e < 8; ++e) {
    gp[e] += __shfl_xor(gp[e], 1);  gp[e] += __shfl_xor(gp[e], 2);
    gp[e] += __shfl_xor(gp[e], 4);  gp[e] += __shfl_xor(gp[e], 8);
    gp[e] += __shfl_xor(gp[e], 16); gp[e] += __shfl_xor(gp[e], 32);
  }
  __shared__ float gred[4][8];
  __shared__ float srw[8], ssc[8];
  if ((tid & 63) == 0) {
#pragma unroll
    for (int e = 0; e < 8; ++e) gred[wave][e] = gp[e];
  }
  __syncthreads();
  if (tid < 8) {
    float lg = gred[0][tid] + gred[1][tid] + gred[2][tid] + gred[3][tid];
    float rw = 1.f / (1.f + expf(-lg));
    srw[tid] = rw;
    ssc[tid] = rw + cb[tid];
  }
  __syncthreads();
  if (tid == 0) {
    int e0 = 0; float b0 = ssc[0];
    for (int e = 1; e < 8; ++e) if (ssc[e] > b0) { b0 = ssc[e]; e0 = e; }
    int e1 = -1; float b1 = -1e30f;
    for (int e = 0; e < 8; ++e) if (e != e0 && ssc[e] > b1) { b1 = ssc[e]; e1 = e; }
    float t0 = srw[e0], t1 = srw[e1], s = t0 + t1;
    sel[row * 2] = e0; sel[row * 2 + 1] = e1;
    tw[row * 2] = t0 / s; tw[row * 2 + 1] = t1 / s;
    atomicAdd(&cnt[e0], 1);
    atomicAdd(&cnt[e1], 1);
  }
}

// ---------------- routing: merged scan + scatter (single block) ---------------------
__global__ __launch_bounds__(256) void k_scan_scatter(const int* cnt, int* eoff,
                                                      int* fill, const int* sel,
                                                      int* rows, int* pos) {
  if (threadIdx.x == 0) {
    int s = 0;
    for (int e = 0; e < 8; ++e) { eoff[e] = s; s += cnt[e]; }
  }
  __syncthreads();
  for (int base = 0; base < 2048; base += 256) {
    int t = base + threadIdx.x;
    for (int k = 0; k < 2; ++k) {
      int e = sel[t * 2 + k];
      int p = eoff[e] + atomicAdd(&fill[e], 1);
      rows[p] = t;
      pos[t * 2 + k] = p;
    }
  }
}

// ---------------- final combine -----------------------------------------------------
__global__ __launch_bounds__(256) void k_combine(float* out, const short* mo,
                                                 const int* pos, const float* tw) {
  int t = blockIdx.x, tid = threadIdx.x;
  int p0 = pos[t * 2], p1 = pos[t * 2 + 1];
  float w0 = tw[t * 2], w1 = tw[t * 2 + 1];
  float* o = out + (long)t * 2048 + tid * 8;
  short8 m0 = *(const short8*)(mo + (long)p0 * 2048 + tid * 8);
  short8 m1 = *(const short8*)(mo + (long)p1 * 2048 + tid * 8);
  float4 a = *(const float4*)o;
  float4 b = *(const float4*)(o + 4);
  a.x += w0 * bf2f(m0[0]) + w1 * bf2f(m1[0]);
  a.y += w0 * bf2f(m0[1]) + w1 * bf2f(m1[1]);
  a.z += w0 * bf2f(m0[2]) + w1 * bf2f(m1[2]);
  a.w += w0 * bf2f(m0[3]) + w1 * bf2f(m1[3]);
  b.x += w0 * bf2f(m0[4]) + w1 * bf2f(m1[4]);
  b.y += w0 * bf2f(m0[5]) + w1 * bf2f(m1[5]);
  b.z += w0 * bf2f(m0[6]) + w1 * bf2f(m1[6]);
  b.w += w0 * bf2f(m0[7]) + w1 * bf2f(m1[7]);
  *(float4*)o = a;
  *(float4*)(o + 4) = b;
}

// ------------------------------------------------------------------------------------
extern "C" void kernel_launch(void* const* d_in, const int* in_sizes, int n_in,
                              void* d_out, int out_size, void* d_ws, size_t ws_size,
                              hipStream_t stream) {
  const float* x    = (const float*)d_in[0];
  const float* cosb = (const float*)d_in[1];
  const float* sinb = (const float*)d_in[2];
  const float* ln1  = (const float*)d_in[3];
  const float* ln2  = (const float*)d_in[4];
  const float* wq   = (const float*)d_in[5];
  const float* wk   = (const float*)d_in[6];
  const float* wv   = (const float*)d_in[7];
  const float* wo   = (const float*)d_in[8];
  const float* gw   = (const float*)d_in[9];
  const float* cb   = (const float*)d_in[10];
  const float* w1   = (const float*)d_in[11];
  const float* w2   = (const float*)d_in[12];
  const float* w3   = (const float*)d_in[13];
  float* out = (float*)d_out;

  char* p = (char*)d_ws;
  auto take = [&](size_t n) { char* r = p; p += (n + 255) & ~(size_t)255; return r; };
  short* qkvTh = (short*)take(3072L * 2048 * 2);
  short* qkvTl = (short*)take(3072L * 2048 * 2);
  short* woTh  = (short*)take(2048L * 2048 * 2);
  short* woTl  = (short*)take(2048L * 2048 * 2);
  short* w1T   = (short*)take(8L * 1024 * 2048 * 2);
  short* w3T   = (short*)take(8L * 1024 * 2048 * 2);
  short* w2T   = (short*)take(8L * 2048 * 1024 * 2);
  short* hbh   = (short*)take(2048L * 2048 * 2);
  short* hbl   = (short*)take(2048L * 2048 * 2);
  short* qbh   = (short*)take(2048L * 2048 * 2);
  short* qbl   = (short*)take(2048L * 2048 * 2);
  short* kbh   = (short*)take(2048L * 512 * 2);
  short* kbl   = (short*)take(2048L * 512 * 2);
  short* vth   = (short*)take(16L * 64 * 1024 * 2);
  short* vtl   = (short*)take(16L * 64 * 1024 * 2);
  short* aoh   = (short*)take(2048L * 2048 * 2);
  short* aol   = (short*)take(2048L * 2048 * 2);
  short* h2b   = (short*)take(2048L * 2048 * 2);
  short* hhb   = (short*)take(4224L * 1024 * 2);
  short* mob   = (short*)take(4352L * 2048 * 2);
  int* rti     = (int*)take(64 * sizeof(int));
  int* cnt = rti; int* fill = rti + 8; int* eoff = rti + 16;
  int* sel     = (int*)take(2048L * 2 * 4);
  float* twb   = (float*)take(2048L * 2 * 4);
  int* rowsp   = (int*)take(4352L * 4);
  int* posb    = (int*)take(2048L * 2 * 4);
  (void)ws_size; (void)in_sizes; (void)n_in; (void)out_size;

  dim3 B256(256);
  k_trans_all<<<dim3(16896), B256, 0, stream>>>(wq, wk, wv, wo, w1, w3, w2,
                                                qkvTh, qkvTl, woTh, woTl,
                                                w1T, w3T, w2T, x, ln1, hbh, hbl);
  hipMemsetAsync(rti, 0, 64, stream);

  k_gemm_qkv<<<dim3(24, 32), B256, 0, stream>>>(hbh, hbl, qkvTh, qkvTl, qbh, qbl,
                                                kbh, kbl, vth, vtl, cosb, sinb);
  k_attn3<<<dim3(8, 64), B256, 0, stream>>>(qbh, qbl, kbh, kbl, vth, vtl, aoh, aol);
  k_gemm_wo<<<dim3(32, 16), B256, 0, stream>>>(aoh, aol, woTh, woTl, x, out);

  k_rmsnorm2_gate<<<dim3(2048), B256, 0, stream>>>(out, ln2, gw, cb, h2b, sel, twb, cnt);
  k_scan_scatter<<<dim3(1), B256, 0, stream>>>(cnt, eoff, fill, sel, rowsp, posb);
  k_moe_a<<<dim3(16, 16, 8), B256, 0, stream>>>(h2b, w1T, w3T, rowsp, cnt, eoff, hhb);
  k_moe_b<<<dim3(16, 16, 8), B256, 0, stream>>>(hhb, w2T, cnt, eoff, mob);
  k_combine<<<dim3(2048), B256, 0, stream>>>(out, mob, posb, twb);
}